// Round 4
// baseline (12716.471 us; speedup 1.0000x reference)
//
#include <hip/hip_runtime.h>
#include <hip/hip_bf16.h>
#include <math.h>

constexpr int LYR = 6;
constexpr int E   = 768;
constexpr int NH  = 12;
constexpr int FFD = 3072;
constexpr int HD  = 64;
constexpr int BB  = 2;
constexpr int SS  = 1024;
constexpr int T   = BB * SS;     // 2048 tokens
constexpr int E3  = 3 * E;       // 2304
constexpr int FH  = FFD / 2;     // 1536 (FFN slice width)

#define LN_EPS 1e-5f

__device__ __forceinline__ float bf2f(__hip_bfloat16 x) { return __bfloat162float(x); }
__device__ __forceinline__ float bfr2f(unsigned short u) {
    union { unsigned int i; float f; } v; v.i = ((unsigned int)u) << 16; return v.f;
}
__device__ __forceinline__ __hip_bfloat16 f2bf(float f) { return __float2bfloat16(f); }

// ---------------- block reductions (256 threads = 4 waves of 64) ----------------
__device__ __forceinline__ float block_sum(float v, float* sm) {
    #pragma unroll
    for (int o = 32; o > 0; o >>= 1) v += __shfl_down(v, o, 64);
    int lane = threadIdx.x & 63, wid = threadIdx.x >> 6;
    if (lane == 0) sm[wid] = v;
    __syncthreads();
    float r = sm[0] + sm[1] + sm[2] + sm[3];
    __syncthreads();
    return r;
}

__device__ __forceinline__ float block_max(float v, float* sm) {
    #pragma unroll
    for (int o = 32; o > 0; o >>= 1) v = fmaxf(v, __shfl_down(v, o, 64));
    int lane = threadIdx.x & 63, wid = threadIdx.x >> 6;
    if (lane == 0) sm[wid] = v;
    __syncthreads();
    float r = fmaxf(fmaxf(sm[0], sm[1]), fmaxf(sm[2], sm[3]));
    __syncthreads();
    return r;
}

// ---------------- f32 copy (embeddings -> residual stream) ----------------
__global__ void copy_kernel(const float* __restrict__ in, float* __restrict__ out, int n) {
    int i = blockIdx.x * 256 + threadIdx.x;
    if (i < n) out[i] = in[i];
}

// ---------------- LayerNorm: one block per row; x f32 -> out bf16 or f32 --------
template <typename OT>
__global__ void ln_kernel(const float* __restrict__ x, OT* __restrict__ out,
                          const float* __restrict__ g,
                          const float* __restrict__ b) {
    __shared__ float sm[4];
    int row = blockIdx.x;
    const float* xr = x + (size_t)row * E;
    float s = 0.f;
    for (int i = threadIdx.x; i < E; i += 256) s += xr[i];
    float mu = block_sum(s, sm) * (1.0f / E);
    float v = 0.f;
    for (int i = threadIdx.x; i < E; i += 256) { float d = xr[i] - mu; v += d * d; }
    float rstd = rsqrtf(block_sum(v, sm) * (1.0f / E) + LN_EPS);
    for (int i = threadIdx.x; i < E; i += 256) {
        float o = (xr[i] - mu) * rstd * g[i] + b[i];
        if constexpr (sizeof(OT) == 2) out[(size_t)row * E + i] = f2bf(o);
        else                           out[(size_t)row * E + i] = o;
    }
}

// ---------------- GEMM: C[M,N] = A[M,K](bf16,lda) @ W[K,N](f32,ldw) + epilogue ---
// FUSE: 0 = +bias, 1 = +bias then exact GELU, 2 = resid + A@W + bias, 3 = resid + A@W
// CT: float or __hip_bfloat16. Requires M%64==0, N%64==0, K%16==0, strides %4==0.
template <int FUSE, typename CT>
__global__ void gemm_kernel(const __hip_bfloat16* __restrict__ A, int lda,
                            const float* __restrict__ W, int ldw,
                            const float* __restrict__ bias,
                            CT* __restrict__ C, int ldc,
                            const float* __restrict__ resid,
                            int M, int N, int K) {
    __shared__ float As[16][65];
    __shared__ float Bs[16][65];
    int bm = blockIdx.y * 64, bn = blockIdx.x * 64;
    int tid = threadIdx.x;
    int ty = tid >> 4, tx = tid & 15;
    int ar = tid >> 2, ak = (tid & 3) << 2;    // A load: row ar (0..63), k offs {0,4,8,12}
    int wk = tid >> 4, wn = (tid & 15) << 2;   // W load: k row wk (0..15), col offs {0..60}

    float acc[4][4] = {};
    for (int k0 = 0; k0 < K; k0 += 16) {
        ushort4 av = *(const ushort4*)(A + (size_t)(bm + ar) * lda + k0 + ak);
        As[ak + 0][ar] = bfr2f(av.x);
        As[ak + 1][ar] = bfr2f(av.y);
        As[ak + 2][ar] = bfr2f(av.z);
        As[ak + 3][ar] = bfr2f(av.w);
        float4 wv = *(const float4*)(W + (size_t)(k0 + wk) * ldw + bn + wn);
        Bs[wk][wn + 0] = wv.x;
        Bs[wk][wn + 1] = wv.y;
        Bs[wk][wn + 2] = wv.z;
        Bs[wk][wn + 3] = wv.w;
        __syncthreads();
        #pragma unroll
        for (int kk = 0; kk < 16; kk++) {
            float a[4], bv[4];
            #pragma unroll
            for (int i = 0; i < 4; i++) { a[i] = As[kk][ty * 4 + i]; bv[i] = Bs[kk][tx * 4 + i]; }
            #pragma unroll
            for (int i = 0; i < 4; i++)
                #pragma unroll
                for (int j = 0; j < 4; j++) acc[i][j] += a[i] * bv[j];
        }
        __syncthreads();
    }
    #pragma unroll
    for (int i = 0; i < 4; i++) {
        int row = bm + ty * 4 + i;
        #pragma unroll
        for (int j = 0; j < 4; j++) {
            int col = bn + tx * 4 + j;
            float v = acc[i][j];
            if (FUSE != 3) v += bias[col];
            if (FUSE == 1) v = 0.5f * v * (1.0f + erff(v * 0.70710678118654752f));
            if (FUSE == 2 || FUSE == 3) v += resid[(size_t)row * ldc + col];
            if constexpr (sizeof(CT) == 2) C[(size_t)row * ldc + col] = f2bf(v);
            else                           C[(size_t)row * ldc + col] = v;
        }
    }
}

// ---------------- Attention (single batch): one block per (h, q) ----------------
// qkv[1024, 3E] bf16; mask[1024] f32; out[1024, E] bf16
__global__ void attn_kernel(const __hip_bfloat16* __restrict__ qkv,
                            const float* __restrict__ mask,
                            __hip_bfloat16* __restrict__ out) {
    __shared__ float sc[SS];
    __shared__ float qv[HD];
    __shared__ float oacc[4][HD];
    __shared__ float redbuf[4];

    int q = blockIdx.x & (SS - 1);
    int h = blockIdx.x >> 10;          // 0..11
    int tid = threadIdx.x;

    const __hip_bfloat16* qrow = qkv + (size_t)q * E3 + h * HD;
    if (tid < HD) qv[tid] = bf2f(qrow[tid]) * 0.125f;   // 1/sqrt(64)
    __syncthreads();

    // scores
    for (int j = tid; j < SS; j += 256) {
        const __hip_bfloat16* krow = qkv + (size_t)j * E3 + E + h * HD;
        float d = 0.f;
        #pragma unroll
        for (int t = 0; t < HD; t += 4) {
            ushort4 kv4 = *(const ushort4*)(krow + t);
            d += qv[t] * bfr2f(kv4.x) + qv[t + 1] * bfr2f(kv4.y)
               + qv[t + 2] * bfr2f(kv4.z) + qv[t + 3] * bfr2f(kv4.w);
        }
        d += (1.0f - mask[j]) * -10000.0f;
        sc[j] = d;
    }
    __syncthreads();

    // softmax
    float m = -1e30f;
    for (int j = tid; j < SS; j += 256) m = fmaxf(m, sc[j]);
    m = block_max(m, redbuf);
    float s = 0.f;
    for (int j = tid; j < SS; j += 256) { float e = __expf(sc[j] - m); sc[j] = e; s += e; }
    s = block_sum(s, redbuf);
    float inv = 1.0f / s;
    __syncthreads();

    // output: thread (chunk c of 4, dim d of 64) accumulates 256 keys
    int d = tid & 63, c = tid >> 6;
    float acc = 0.f;
    int j0 = c * 256;
    for (int j = j0; j < j0 + 256; j++) {
        const __hip_bfloat16* vrow = qkv + (size_t)j * E3 + 2 * E + h * HD;
        acc += sc[j] * bf2f(vrow[d]);
    }
    oacc[c][d] = acc;
    __syncthreads();
    if (tid < HD) {
        float o = (oacc[0][tid] + oacc[1][tid] + oacc[2][tid] + oacc[3][tid]) * inv;
        out[(size_t)q * E + h * HD + tid] = f2bf(o);
    }
}

extern "C" void kernel_launch(void* const* d_in, const int* in_sizes, int n_in,
                              void* d_out, int out_size, void* d_ws, size_t ws_size,
                              hipStream_t stream) {
    // Reference dtypes are float32 throughout (setup_inputs uses jnp.float32).
    const float* emb   = (const float*)d_in[0];
    const float* mask  = (const float*)d_in[1];
    const float* Wqkv  = (const float*)d_in[2];
    const float* bqkv  = (const float*)d_in[3];
    const float* Wo    = (const float*)d_in[4];
    const float* bo    = (const float*)d_in[5];
    const float* ln1g  = (const float*)d_in[6];
    const float* ln1b  = (const float*)d_in[7];
    const float* ln2g  = (const float*)d_in[8];
    const float* ln2b  = (const float*)d_in[9];
    const float* Wfc   = (const float*)d_in[10];
    const float* bfc   = (const float*)d_in[11];
    const float* Wmo   = (const float*)d_in[12];
    const float* bmo   = (const float*)d_in[13];
    const float* lnfg  = (const float*)d_in[14];
    const float* lnfb  = (const float*)d_in[15];

    // workspace (12.58 MB total):
    //   x   f32  [T,E]                 6.29 MB   residual stream
    //   buf bf16 region                6.29 MB   per-phase scratch:
    //     attn phase (per batch): hb_b [1024,E] + qkv_b [1024,E3]
    //     ffn  phase (per batch): hb_b [1024,E] + ffp   [1024,FH]
    float* x           = (float*)d_ws;
    __hip_bfloat16* hb = (__hip_bfloat16*)(x + (size_t)T * E);   // 1024*E slot
    __hip_bfloat16* qb = hb + (size_t)1024 * E;                  // qkv_b / ffp slot

    {   // x = inputs_embeds (mutable residual stream)
        int n = T * E;
        copy_kernel<<<dim3((n + 255) / 256), dim3(256), 0, stream>>>(emb, x, n);
    }

    for (int l = 0; l < LYR; l++) {
        const float* wqkv_l = Wqkv + (size_t)l * E * E3;
        const float* wo_l   = Wo   + (size_t)l * E * E;
        const float* wfc_l  = Wfc  + (size_t)l * E * FFD;
        const float* wmo_l  = Wmo  + (size_t)l * FFD * E;

        // ---- attention sublayer, per batch ----
        for (int b = 0; b < BB; b++) {
            float* xb = x + (size_t)b * SS * E;
            // hb = LN1(x_b)
            ln_kernel<__hip_bfloat16><<<dim3(SS), dim3(256), 0, stream>>>(
                xb, hb, ln1g + l * E, ln1b + l * E);
            // qb = hb @ Wqkv + bqkv     [1024, E3]
            gemm_kernel<0, __hip_bfloat16><<<dim3(E3 / 64, SS / 64), dim3(256), 0, stream>>>(
                hb, E, wqkv_l, E3, bqkv + l * E3, qb, E3, nullptr, SS, E3, E);
            // hb = attention(qb)        [1024, E]  (hb's LN1 contents are dead)
            attn_kernel<<<dim3(NH * SS), dim3(256), 0, stream>>>(qb, mask + b * SS, hb);
            // x_b = x_b + hb @ Wo + bo
            gemm_kernel<2, float><<<dim3(E / 64, SS / 64), dim3(256), 0, stream>>>(
                hb, E, wo_l, E, bo + l * E, xb, E, xb, SS, E, E);
        }

        // ---- FFN sublayer, per batch, FFD split in two 1536 slices ----
        for (int b = 0; b < BB; b++) {
            float* xb = x + (size_t)b * SS * E;
            // hb = LN2(x_b)
            ln_kernel<__hip_bfloat16><<<dim3(SS), dim3(256), 0, stream>>>(
                xb, hb, ln2g + l * E, ln2b + l * E);
            for (int f = 0; f < 2; f++) {
                // qb = gelu(hb @ Wfc[:, f*FH:(f+1)*FH] + bfc[f*FH:])   [1024, FH]
                gemm_kernel<1, __hip_bfloat16><<<dim3(FH / 64, SS / 64), dim3(256), 0, stream>>>(
                    hb, E, wfc_l + f * FH, FFD, bfc + l * FFD + f * FH, qb, FH, nullptr,
                    SS, FH, E);
                // x_b += qb @ Wmo[f*FH:(f+1)*FH, :]  (+ bmo on last slice)
                if (f == 0)
                    gemm_kernel<3, float><<<dim3(E / 64, SS / 64), dim3(256), 0, stream>>>(
                        qb, FH, wmo_l + (size_t)f * FH * E, E, nullptr, xb, E, xb, SS, E, FH);
                else
                    gemm_kernel<2, float><<<dim3(E / 64, SS / 64), dim3(256), 0, stream>>>(
                        qb, FH, wmo_l + (size_t)f * FH * E, E, bmo + l * E, xb, E, xb, SS, E, FH);
            }
        }
    }

    // out = LN_f(x) in f32 (reference output dtype)
    ln_kernel<float><<<dim3(T), dim3(256), 0, stream>>>(x, (float*)d_out, lnfg, lnfb);
}

// Round 6
// 4739.438 us; speedup vs baseline: 2.6831x; 2.6831x over previous
//
#include <hip/hip_runtime.h>
#include <hip/hip_bf16.h>
#include <math.h>

constexpr int LYR = 6;
constexpr int E   = 768;
constexpr int NH  = 12;
constexpr int FFD = 3072;
constexpr int HD  = 64;
constexpr int BB  = 2;
constexpr int SS  = 1024;
constexpr int T   = BB * SS;     // 2048 tokens
constexpr int E3  = 3 * E;       // 2304
constexpr int FH  = FFD / 2;     // 1536 (FFN slice width)

#define LN_EPS 1e-5f

typedef __attribute__((ext_vector_type(8))) short    short8v;
typedef __attribute__((ext_vector_type(8))) unsigned short ushort8v;
typedef __attribute__((ext_vector_type(4))) unsigned short ushort4v;
typedef __attribute__((ext_vector_type(4))) float    f32x4;

__device__ __forceinline__ float bf2f(__hip_bfloat16 x) { return __bfloat162float(x); }
__device__ __forceinline__ float bfr2f(unsigned short u) {
    union { unsigned int i; float f; } v; v.i = ((unsigned int)u) << 16; return v.f;
}
__device__ __forceinline__ __hip_bfloat16 f2bf(float f) { return __float2bfloat16(f); }
// bf16 bits with round-to-nearest-even (finite inputs only)
__device__ __forceinline__ unsigned short f2bfbits(float f) {
    union { float f; unsigned int i; } v; v.f = f;
    unsigned int r = (v.i + 0x7fffu + ((v.i >> 16) & 1u)) >> 16;
    return (unsigned short)r;
}

// ---------------- block reductions (256 threads = 4 waves of 64) ----------------
__device__ __forceinline__ float block_sum(float v, float* sm) {
    #pragma unroll
    for (int o = 32; o > 0; o >>= 1) v += __shfl_down(v, o, 64);
    int lane = threadIdx.x & 63, wid = threadIdx.x >> 6;
    if (lane == 0) sm[wid] = v;
    __syncthreads();
    float r = sm[0] + sm[1] + sm[2] + sm[3];
    __syncthreads();
    return r;
}

__device__ __forceinline__ float block_max(float v, float* sm) {
    #pragma unroll
    for (int o = 32; o > 0; o >>= 1) v = fmaxf(v, __shfl_down(v, o, 64));
    int lane = threadIdx.x & 63, wid = threadIdx.x >> 6;
    if (lane == 0) sm[wid] = v;
    __syncthreads();
    float r = fmaxf(fmaxf(sm[0], sm[1]), fmaxf(sm[2], sm[3]));
    __syncthreads();
    return r;
}

// ---------------- f32 copy (embeddings -> residual stream), float4 ----------------
__global__ void copy4_kernel(const float4* __restrict__ in, float4* __restrict__ out, int n4) {
    int i = blockIdx.x * 256 + threadIdx.x;
    if (i < n4) out[i] = in[i];
}

// ---------------- per-row LN stats: musig[row] = (mu, rstd) ----------------
__global__ void rowstat_kernel(const float* __restrict__ x, float2* __restrict__ musig) {
    __shared__ float sm[4];
    int row = blockIdx.x;
    const float* xr = x + (size_t)row * E;
    float s = 0.f;
    for (int i = threadIdx.x; i < E; i += 256) s += xr[i];
    float mu = block_sum(s, sm) * (1.0f / E);
    float v = 0.f;
    for (int i = threadIdx.x; i < E; i += 256) { float d = xr[i] - mu; v += d * d; }
    float rstd = rsqrtf(block_sum(v, sm) * (1.0f / E) + LN_EPS);
    if (threadIdx.x == 0) musig[row] = make_float2(mu, rstd);
}

// ---------------- LayerNorm: one block per row; x f32 -> out bf16 or f32 --------
template <typename OT>
__global__ void ln_kernel(const float* __restrict__ x, OT* __restrict__ out,
                          const float* __restrict__ g, const float* __restrict__ b) {
    __shared__ float sm[4];
    int row = blockIdx.x;
    const float* xr = x + (size_t)row * E;
    float s = 0.f;
    for (int i = threadIdx.x; i < E; i += 256) s += xr[i];
    float mu = block_sum(s, sm) * (1.0f / E);
    float v = 0.f;
    for (int i = threadIdx.x; i < E; i += 256) { float d = xr[i] - mu; v += d * d; }
    float rstd = rsqrtf(block_sum(v, sm) * (1.0f / E) + LN_EPS);
    for (int i = threadIdx.x; i < E; i += 256) {
        float o = (xr[i] - mu) * rstd * g[i] + b[i];
        if constexpr (sizeof(OT) == 2) out[(size_t)row * E + i] = f2bf(o);
        else                           out[(size_t)row * E + i] = o;
    }
}

// =================================================================================
// MFMA GEMM: C[M,N] = A' @ W + epilogue, tile 128x128, BK=32, 256 thr (4 waves 2x2)
//   AMODE 0: A' = bf16 bits global [m][k] stride lda
//   AMODE 1: A' = layernorm(x f32 [m][k] lda) via musig[m], lng/lnb[k]
//            (NOTE: only safe if nothing mutates x between rowstat and this GEMM)
//   FUSE  0: C = A'@W + bias                 -> bf16 bits C
//   FUSE  1: C = gelu(A'@W + bias)           -> bf16 bits C
//   FUSE  2: C = C + A'@W + bias             -> f32 C (in-place residual)
//   FUSE  3: C = C + A'@W                    -> f32 C
// Requires M%128==0, N%128==0, K%32==0.
// =================================================================================
template <int AMODE, int FUSE>
__global__ void gemm_mfma(const void* __restrict__ Aptr, int lda,
                          const float* __restrict__ W, int ldw,
                          const float* __restrict__ bias,
                          const float2* __restrict__ musig,
                          const float* __restrict__ lng, const float* __restrict__ lnb,
                          void* __restrict__ Cptr, int ldc, int K) {
    __shared__ unsigned short As[128 * 40];   // [m][k'] padded rows (80B, 16B-aligned)
    __shared__ unsigned short Bs[32 * 130];   // [k][n] padded rows (260B -> odd bank stride)

    int tid = threadIdx.x;
    int bm = blockIdx.y * 128, bn = blockIdx.x * 128;
    int w = tid >> 6, lane = tid & 63, ln16 = lane & 15, q = lane >> 4;
    int wm = (w & 1) * 64, wn = (w >> 1) * 64;

    f32x4 acc[4][4];
    #pragma unroll
    for (int i = 0; i < 4; i++)
        #pragma unroll
        for (int j = 0; j < 4; j++) acc[i][j] = (f32x4){0.f, 0.f, 0.f, 0.f};

    for (int k0 = 0; k0 < K; k0 += 32) {
        // ---- stage A ----
        if (AMODE == 0) {
            const unsigned short* A = (const unsigned short*)Aptr;
            #pragma unroll
            for (int i = 0; i < 2; i++) {
                int idx = tid + i * 256;              // 0..511
                int row = idx >> 2, ko = (idx & 3) * 8;
                ushort8v v = *(const ushort8v*)(A + (size_t)(bm + row) * lda + k0 + ko);
                *(ushort8v*)(&As[row * 40 + ko]) = v;
            }
        } else {
            const float* A = (const float*)Aptr;
            #pragma unroll
            for (int i = 0; i < 4; i++) {
                int idx = tid + i * 256;              // 0..1023
                int row = idx >> 3, ko = (idx & 7) * 4;
                float4 xv = *(const float4*)(A + (size_t)(bm + row) * lda + k0 + ko);
                float2 ms = musig[bm + row];
                float4 gv = *(const float4*)(lng + k0 + ko);
                float4 bv = *(const float4*)(lnb + k0 + ko);
                ushort4v o;
                o[0] = f2bfbits((xv.x - ms.x) * ms.y * gv.x + bv.x);
                o[1] = f2bfbits((xv.y - ms.x) * ms.y * gv.y + bv.y);
                o[2] = f2bfbits((xv.z - ms.x) * ms.y * gv.z + bv.z);
                o[3] = f2bfbits((xv.w - ms.x) * ms.y * gv.w + bv.w);
                *(ushort4v*)(&As[row * 40 + ko]) = o;
            }
        }
        // ---- stage B (f32 -> bf16, natural k-major layout) ----
        #pragma unroll
        for (int i = 0; i < 16; i++) {
            int idx = tid + i * 256;                  // 0..4095
            int kr = idx >> 7, n = idx & 127;
            float wv = W[(size_t)(k0 + kr) * ldw + bn + n];
            Bs[kr * 130 + n] = f2bfbits(wv);
        }
        __syncthreads();

        // ---- fragments + MFMA ----
        short8v afr[4], bfr[4];
        #pragma unroll
        for (int i = 0; i < 4; i++)
            afr[i] = *(const short8v*)(&As[(wm + i * 16 + ln16) * 40 + q * 8]);
        #pragma unroll
        for (int j = 0; j < 4; j++) {
            int n = wn + j * 16 + ln16;
            #pragma unroll
            for (int jj = 0; jj < 8; jj++)
                bfr[j][jj] = (short)Bs[(q * 8 + jj) * 130 + n];
        }
        #pragma unroll
        for (int i = 0; i < 4; i++)
            #pragma unroll
            for (int j = 0; j < 4; j++)
                acc[i][j] = __builtin_amdgcn_mfma_f32_16x16x32_bf16(afr[i], bfr[j], acc[i][j], 0, 0, 0);
        __syncthreads();
    }

    // ---- epilogue ----
    #pragma unroll
    for (int j = 0; j < 4; j++) {
        int col = bn + wn + j * 16 + ln16;
        float bv = (FUSE == 3) ? 0.f : bias[col];
        #pragma unroll
        for (int i = 0; i < 4; i++) {
            #pragma unroll
            for (int r = 0; r < 4; r++) {
                int row = bm + wm + i * 16 + q * 4 + r;
                float v = acc[i][j][r] + bv;
                if (FUSE == 1) v = 0.5f * v * (1.0f + erff(v * 0.70710678118654752f));
                if (FUSE == 0 || FUSE == 1) {
                    ((unsigned short*)Cptr)[(size_t)row * ldc + col] = f2bfbits(v);
                } else {
                    float* C = (float*)Cptr;
                    C[(size_t)row * ldc + col] += v;
                }
            }
        }
    }
}

// =================================================================================
// Flash attention: one block per (b, h, 32-query tile); qkv bf16 bits [T][E3].
// Output written IN PLACE into the q-slot (cols h*64..h*64+63 of rows owned).
// =================================================================================
__global__ void attn_flash(unsigned short* __restrict__ qkv,
                           const float* __restrict__ mask) {
    __shared__ float Qs[32][68];
    __shared__ float Ks[64][68];
    __shared__ float Vs[64][68];
    __shared__ float Ps[32][68];

    int bid = blockIdx.x;                 // b(2) x h(12) x qt(32)
    int qt = bid & 31;
    int h  = (bid >> 5) % NH;
    int b  = bid / (32 * NH);
    int tid = threadIdx.x;
    int ql = tid >> 3, grp = tid & 7;     // scores: jg=grp; PV: dg=grp

    // load Q (scaled)
    #pragma unroll
    for (int i = 0; i < 8; i++) {
        int idx = tid + i * 256;          // 0..2047
        int rq = idx >> 6, d = idx & 63;
        int grow = b * SS + qt * 32 + rq;
        Qs[rq][d] = bfr2f(qkv[(size_t)grow * E3 + h * HD + d]) * 0.125f;
    }

    float m_run = -1e30f, l_run = 0.f;
    float O[8] = {0.f, 0.f, 0.f, 0.f, 0.f, 0.f, 0.f, 0.f};

    for (int c = 0; c < 16; c++) {
        int j0 = c * 64;
        // stage K, V (64x64 each), bf16 -> f32
        #pragma unroll
        for (int i = 0; i < 4; i++) {
            int idx = tid + i * 256;      // 0..1023
            int jj = idx >> 4, d4 = (idx & 15) * 4;
            size_t base = (size_t)(b * SS + j0 + jj) * E3 + h * HD + d4;
            ushort4v kv = *(const ushort4v*)(qkv + base + E);
            ushort4v vv = *(const ushort4v*)(qkv + base + 2 * E);
            *(float4*)&Ks[jj][d4] = make_float4(bfr2f(kv[0]), bfr2f(kv[1]), bfr2f(kv[2]), bfr2f(kv[3]));
            *(float4*)&Vs[jj][d4] = make_float4(bfr2f(vv[0]), bfr2f(vv[1]), bfr2f(vv[2]), bfr2f(vv[3]));
        }
        __syncthreads();

        // scores: thread (ql, grp) covers jj = grp + 8*jl
        float s[8] = {0.f, 0.f, 0.f, 0.f, 0.f, 0.f, 0.f, 0.f};
        #pragma unroll
        for (int d0 = 0; d0 < 64; d0 += 4) {
            float4 q4 = *(const float4*)&Qs[ql][d0];
            #pragma unroll
            for (int jl = 0; jl < 8; jl++) {
                float4 k4 = *(const float4*)&Ks[grp + jl * 8][d0];
                s[jl] += q4.x * k4.x + q4.y * k4.y + q4.z * k4.z + q4.w * k4.w;
            }
        }
        #pragma unroll
        for (int jl = 0; jl < 8; jl++)
            s[jl] += (1.0f - mask[b * SS + j0 + grp + jl * 8]) * -10000.0f;

        // chunk max over this q row (8 lanes share a row)
        float cm = s[0];
        #pragma unroll
        for (int jl = 1; jl < 8; jl++) cm = fmaxf(cm, s[jl]);
        cm = fmaxf(cm, __shfl_xor(cm, 1, 64));
        cm = fmaxf(cm, __shfl_xor(cm, 2, 64));
        cm = fmaxf(cm, __shfl_xor(cm, 4, 64));

        float mnew = fmaxf(m_run, cm);
        float alpha = __expf(m_run - mnew);
        float ps = 0.f;
        #pragma unroll
        for (int jl = 0; jl < 8; jl++) {
            float p = __expf(s[jl] - mnew);
            Ps[ql][grp + jl * 8] = p;
            ps += p;
        }
        ps += __shfl_xor(ps, 1, 64);
        ps += __shfl_xor(ps, 2, 64);
        ps += __shfl_xor(ps, 4, 64);
        l_run = l_run * alpha + ps;
        m_run = mnew;
        #pragma unroll
        for (int e = 0; e < 8; e++) O[e] *= alpha;

        // PV: thread (ql, dg=grp) accumulates d = grp*8 + e  (Ps same-wave produced)
        #pragma unroll 4
        for (int jj = 0; jj < 64; jj++) {
            float p = Ps[ql][jj];
            float4 v0 = *(const float4*)&Vs[jj][grp * 8];
            float4 v1 = *(const float4*)&Vs[jj][grp * 8 + 4];
            O[0] += p * v0.x; O[1] += p * v0.y; O[2] += p * v0.z; O[3] += p * v0.w;
            O[4] += p * v1.x; O[5] += p * v1.y; O[6] += p * v1.z; O[7] += p * v1.w;
        }
        __syncthreads();
    }

    float inv = 1.0f / l_run;
    int grow = b * SS + qt * 32 + ql;
    size_t obase = (size_t)grow * E3 + h * HD + grp * 8;
    #pragma unroll
    for (int e = 0; e < 8; e++)
        qkv[obase + e] = f2bfbits(O[e] * inv);
}

// =================================================================================
// Legacy (R4-proven) kernels — fallback if workspace is too small for fast path
// =================================================================================
template <int FUSE, typename CT>
__global__ void gemm_legacy(const __hip_bfloat16* __restrict__ A, int lda,
                            const float* __restrict__ W, int ldw,
                            const float* __restrict__ bias,
                            CT* __restrict__ C, int ldc,
                            const float* __restrict__ resid,
                            int M, int N, int K) {
    __shared__ float As[16][65];
    __shared__ float Bs[16][65];
    int bm = blockIdx.y * 64, bn = blockIdx.x * 64;
    int tid = threadIdx.x;
    int ty = tid >> 4, tx = tid & 15;
    int ar = tid >> 2, ak = (tid & 3) << 2;
    int wk = tid >> 4, wn = (tid & 15) << 2;

    float acc[4][4] = {};
    for (int k0 = 0; k0 < K; k0 += 16) {
        ushort4 av = *(const ushort4*)(A + (size_t)(bm + ar) * lda + k0 + ak);
        As[ak + 0][ar] = bfr2f(av.x);
        As[ak + 1][ar] = bfr2f(av.y);
        As[ak + 2][ar] = bfr2f(av.z);
        As[ak + 3][ar] = bfr2f(av.w);
        float4 wv = *(const float4*)(W + (size_t)(k0 + wk) * ldw + bn + wn);
        Bs[wk][wn + 0] = wv.x;
        Bs[wk][wn + 1] = wv.y;
        Bs[wk][wn + 2] = wv.z;
        Bs[wk][wn + 3] = wv.w;
        __syncthreads();
        #pragma unroll
        for (int kk = 0; kk < 16; kk++) {
            float a[4], bv[4];
            #pragma unroll
            for (int i = 0; i < 4; i++) { a[i] = As[kk][ty * 4 + i]; bv[i] = Bs[kk][tx * 4 + i]; }
            #pragma unroll
            for (int i = 0; i < 4; i++)
                #pragma unroll
                for (int j = 0; j < 4; j++) acc[i][j] += a[i] * bv[j];
        }
        __syncthreads();
    }
    #pragma unroll
    for (int i = 0; i < 4; i++) {
        int row = bm + ty * 4 + i;
        #pragma unroll
        for (int j = 0; j < 4; j++) {
            int col = bn + tx * 4 + j;
            float v = acc[i][j];
            if (FUSE != 3) v += bias[col];
            if (FUSE == 1) v = 0.5f * v * (1.0f + erff(v * 0.70710678118654752f));
            if (FUSE == 2 || FUSE == 3) v += resid[(size_t)row * ldc + col];
            if constexpr (sizeof(CT) == 2) C[(size_t)row * ldc + col] = f2bf(v);
            else                           C[(size_t)row * ldc + col] = v;
        }
    }
}

__global__ void attn_legacy(const __hip_bfloat16* __restrict__ qkv,
                            const float* __restrict__ mask,
                            __hip_bfloat16* __restrict__ out) {
    __shared__ float sc[SS];
    __shared__ float qv[HD];
    __shared__ float oacc[4][HD];
    __shared__ float redbuf[4];

    int q = blockIdx.x & (SS - 1);
    int h = blockIdx.x >> 10;
    int tid = threadIdx.x;

    const __hip_bfloat16* qrow = qkv + (size_t)q * E3 + h * HD;
    if (tid < HD) qv[tid] = bf2f(qrow[tid]) * 0.125f;
    __syncthreads();

    for (int j = tid; j < SS; j += 256) {
        const __hip_bfloat16* krow = qkv + (size_t)j * E3 + E + h * HD;
        float d = 0.f;
        #pragma unroll
        for (int t = 0; t < HD; t += 4) {
            ushort4 kv4 = *(const ushort4*)(krow + t);
            d += qv[t] * bfr2f(kv4.x) + qv[t + 1] * bfr2f(kv4.y)
               + qv[t + 2] * bfr2f(kv4.z) + qv[t + 3] * bfr2f(kv4.w);
        }
        d += (1.0f - mask[j]) * -10000.0f;
        sc[j] = d;
    }
    __syncthreads();

    float m = -1e30f;
    for (int j = tid; j < SS; j += 256) m = fmaxf(m, sc[j]);
    m = block_max(m, redbuf);
    float s = 0.f;
    for (int j = tid; j < SS; j += 256) { float e = __expf(sc[j] - m); sc[j] = e; s += e; }
    s = block_sum(s, redbuf);
    float inv = 1.0f / s;
    __syncthreads();

    int d = tid & 63, c = tid >> 6;
    float acc = 0.f;
    int j0 = c * 256;
    for (int j = j0; j < j0 + 256; j++) {
        const __hip_bfloat16* vrow = qkv + (size_t)j * E3 + 2 * E + h * HD;
        acc += sc[j] * bf2f(vrow[d]);
    }
    oacc[c][d] = acc;
    __syncthreads();
    if (tid < HD) {
        float o = (oacc[0][tid] + oacc[1][tid] + oacc[2][tid] + oacc[3][tid]) * inv;
        out[(size_t)q * E + h * HD + tid] = f2bf(o);
    }
}

__global__ void copy_kernel(const float* __restrict__ in, float* __restrict__ out, int n) {
    int i = blockIdx.x * 256 + threadIdx.x;
    if (i < n) out[i] = in[i];
}

// =================================================================================
extern "C" void kernel_launch(void* const* d_in, const int* in_sizes, int n_in,
                              void* d_out, int out_size, void* d_ws, size_t ws_size,
                              hipStream_t stream) {
    const float* emb   = (const float*)d_in[0];
    const float* mask  = (const float*)d_in[1];
    const float* Wqkv  = (const float*)d_in[2];
    const float* bqkv  = (const float*)d_in[3];
    const float* Wo    = (const float*)d_in[4];
    const float* bo    = (const float*)d_in[5];
    const float* ln1g  = (const float*)d_in[6];
    const float* ln1b  = (const float*)d_in[7];
    const float* ln2g  = (const float*)d_in[8];
    const float* ln2b  = (const float*)d_in[9];
    const float* Wfc   = (const float*)d_in[10];
    const float* bfc   = (const float*)d_in[11];
    const float* Wmo   = (const float*)d_in[12];
    const float* bmo   = (const float*)d_in[13];
    const float* lnfg  = (const float*)d_in[14];
    const float* lnfb  = (const float*)d_in[15];

    // fast path needs: x f32 [T][E] + qkv bf16 [T][E3] + musig [T] float2
    const size_t NEED_FAST = sizeof(float) * (size_t)T * E
                           + 2 * (size_t)T * E3
                           + sizeof(float2) * (size_t)T;

    if (ws_size >= NEED_FAST) {
        // ---------------- FAST PATH ----------------
        float* x              = (float*)d_ws;
        unsigned short* qkv   = (unsigned short*)(x + (size_t)T * E);   // [T,E3] region
        float2* musig         = (float2*)(qkv + (size_t)T * E3);

        copy4_kernel<<<dim3(T * E / 4 / 256), dim3(256), 0, stream>>>(
            (const float4*)emb, (float4*)x, T * E / 4);

        for (int l = 0; l < LYR; l++) {
            const float* wqkv_l = Wqkv + (size_t)l * E * E3;
            const float* wo_l   = Wo   + (size_t)l * E * E;
            const float* wfc_l  = Wfc  + (size_t)l * E * FFD;
            const float* wmo_l  = Wmo  + (size_t)l * FFD * E;

            // LN1 stats (x is not mutated again before the QKV GEMM -> fusion safe)
            rowstat_kernel<<<dim3(T), dim3(256), 0, stream>>>(x, musig);
            // qkv = LN1(x) @ Wqkv + bqkv           [T, E3] bf16
            gemm_mfma<1, 0><<<dim3(E3 / 128, T / 128), dim3(256), 0, stream>>>(
                x, E, wqkv_l, E3, bqkv + l * E3, musig, ln1g + l * E, ln1b + l * E,
                qkv, E3, E);
            // attention in-place (o -> q slot)
            attn_flash<<<dim3(BB * NH * 32), dim3(256), 0, stream>>>(qkv, mask);
            // x += attnout @ Wo + bo
            gemm_mfma<0, 2><<<dim3(E / 128, T / 128), dim3(256), 0, stream>>>(
                qkv, E3, wo_l, E, bo + l * E, nullptr, nullptr, nullptr, x, E, E);

            // ---- FFN: materialize h = LN2(x) ONCE (R5 bug: slice-0's x-update
            //      polluted slice-1's re-fused LN2). h lives in the tail of the
            //      qkv region; ff in the head. T*FH + T*E == T*E3 exactly. ----
            unsigned short* ff = qkv;                       // [T, FH]
            unsigned short* h  = qkv + (size_t)T * FH;      // [T, E]
            ln_kernel<__hip_bfloat16><<<dim3(T), dim3(256), 0, stream>>>(
                x, (__hip_bfloat16*)h, ln2g + l * E, ln2b + l * E);
            for (int f = 0; f < 2; f++) {
                // ff = gelu(h @ Wfc[:, f*FH:(f+1)*FH] + bfc_f)
                gemm_mfma<0, 1><<<dim3(FH / 128, T / 128), dim3(256), 0, stream>>>(
                    h, E, wfc_l + f * FH, FFD, bfc + l * FFD + f * FH,
                    nullptr, nullptr, nullptr, ff, FH, E);
                // x += ff @ Wmo[f*FH:(f+1)*FH, :]  (+ bmo on last slice)
                if (f == 0)
                    gemm_mfma<0, 3><<<dim3(E / 128, T / 128), dim3(256), 0, stream>>>(
                        ff, FH, wmo_l + (size_t)f * FH * E, E, nullptr, nullptr, nullptr, nullptr,
                        x, E, FH);
                else
                    gemm_mfma<0, 2><<<dim3(E / 128, T / 128), dim3(256), 0, stream>>>(
                        ff, FH, wmo_l + (size_t)f * FH * E, E, bmo + l * E, nullptr, nullptr, nullptr,
                        x, E, FH);
            }
        }
        ln_kernel<float><<<dim3(T), dim3(256), 0, stream>>>(x, (float*)d_out, lnfg, lnfb);
    } else {
        // ---------------- LEGACY PATH (R4-proven, 12.58 MB) ----------------
        float* x           = (float*)d_ws;
        __hip_bfloat16* hb = (__hip_bfloat16*)(x + (size_t)T * E);
        __hip_bfloat16* qb = hb + (size_t)SS * E;

        int n = T * E;
        copy_kernel<<<dim3((n + 255) / 256), dim3(256), 0, stream>>>(emb, x, n);

        for (int l = 0; l < LYR; l++) {
            const float* wqkv_l = Wqkv + (size_t)l * E * E3;
            const float* wo_l   = Wo   + (size_t)l * E * E;
            const float* wfc_l  = Wfc  + (size_t)l * E * FFD;
            const float* wmo_l  = Wmo  + (size_t)l * FFD * E;

            for (int b = 0; b < BB; b++) {
                float* xb = x + (size_t)b * SS * E;
                ln_kernel<__hip_bfloat16><<<dim3(SS), dim3(256), 0, stream>>>(
                    xb, hb, ln1g + l * E, ln1b + l * E);
                gemm_legacy<0, __hip_bfloat16><<<dim3(E3 / 64, SS / 64), dim3(256), 0, stream>>>(
                    hb, E, wqkv_l, E3, bqkv + l * E3, qb, E3, nullptr, SS, E3, E);
                attn_legacy<<<dim3(NH * SS), dim3(256), 0, stream>>>(qb, mask + b * SS, hb);
                gemm_legacy<2, float><<<dim3(E / 64, SS / 64), dim3(256), 0, stream>>>(
                    hb, E, wo_l, E, bo + l * E, xb, E, xb, SS, E, E);
            }
            for (int b = 0; b < BB; b++) {
                float* xb = x + (size_t)b * SS * E;
                ln_kernel<__hip_bfloat16><<<dim3(SS), dim3(256), 0, stream>>>(
                    xb, hb, ln2g + l * E, ln2b + l * E);
                for (int f = 0; f < 2; f++) {
                    gemm_legacy<1, __hip_bfloat16><<<dim3(FH / 64, SS / 64), dim3(256), 0, stream>>>(
                        hb, E, wfc_l + f * FH, FFD, bfc + l * FFD + f * FH, qb, FH, nullptr,
                        SS, FH, E);
                    if (f == 0)
                        gemm_legacy<3, float><<<dim3(E / 64, SS / 64), dim3(256), 0, stream>>>(
                            qb, FH, wmo_l + (size_t)f * FH * E, E, nullptr, xb, E, xb, SS, E, FH);
                    else
                        gemm_legacy<2, float><<<dim3(E / 64, SS / 64), dim3(256), 0, stream>>>(
                            qb, FH, wmo_l + (size_t)f * FH * E, E, bmo + l * E, xb, E, xb, SS, E, FH);
                }
            }
        }
        ln_kernel<float><<<dim3(T), dim3(256), 0, stream>>>(x, (float*)d_out, lnfg, lnfb);
    }
}